// Round 6
// baseline (261.277 us; speedup 1.0000x reference)
//
#include <hip/hip_runtime.h>
#include <hip/hip_bf16.h>
#include <math.h>

// ---------------- problem constants ----------------
#define L_SEQ 4096            // H*W
#define NB    4
#define DIMC  192
#define DIN   384             // d_inner
#define DIN2  768
#define DTRANK 12
#define DSTATE 16
#define NKX   44              // dt_rank + 2*d_state
#define G_CHUNKS 128
#define T_CHUNK  32           // L_SEQ / G_CHUNKS
#define NCH  (NB*DIN*DSTATE)  // 24576 scan channels
#define NM   (NB*L_SEQ)       // 16384 (b,l) rows
#define NBIG 512              // padded rows of fused x_proj weight (32 BC + 384 dt + pad)

typedef __attribute__((ext_vector_type(8))) short short8;     // 8 bf16 = 4 VGPRs
typedef __attribute__((ext_vector_type(4))) float floatx4;

__device__ __forceinline__ float silu_f(float v) {
    return v / (1.f + __expf(-v));
}
__device__ __forceinline__ float softplus_f(float v) {
    return fmaxf(v, 0.f) + log1pf(__expf(-fabsf(v)));
}

// async global->LDS 16B per lane (wave-uniform LDS base + lane*16 required)
#define GLOAD_LDS16(g, l)                                                       \
    __builtin_amdgcn_global_load_lds(                                           \
        (const __attribute__((address_space(1))) unsigned int*)(uintptr_t)(g),  \
        (__attribute__((address_space(3))) unsigned int*)(unsigned int)(uintptr_t)(l), \
        16, 0, 0)

// ---------------- convert + transpose x: (b,c,l) f32 -> (b*l, c) bf16 ----------------
__launch_bounds__(256)
__global__ void k_cvt_x(const float* __restrict__ x, __hip_bfloat16* __restrict__ xb) {
    __shared__ float s[32][33];
    const int b = blockIdx.z, c0 = blockIdx.y * 32, l0 = blockIdx.x * 32;
    const int tx = threadIdx.x, ty = threadIdx.y;   // (32, 8)
    const float* xp = x + ((size_t)b * DIMC + c0) * L_SEQ + l0;
#pragma unroll
    for (int r = 0; r < 4; ++r)
        s[ty + r*8][tx] = xp[(size_t)(ty + r*8) * L_SEQ + tx];
    __syncthreads();
    __hip_bfloat16* op = xb + ((size_t)b * L_SEQ + l0) * DIMC + c0;
#pragma unroll
    for (int r = 0; r < 4; ++r) {
        const int lr = ty + r*8;
        op[(size_t)lr * DIMC + tx] = __float2bfloat16(s[tx][lr]);
    }
}

// ------- weights: W_in, W_out -> bf16; build Wbig(512x384) = [Wx[12:44]; Wdt@Wx[:12]; 0] ----
#define NWI (DIN2*DIMC)        // 147456
#define NWO (DIMC*DIN)         // 73728
#define NWBIG (NBIG*DIN)       // 196608
__launch_bounds__(256)
__global__ void k_cvt_w(const float* __restrict__ W_in, const float* __restrict__ W_out,
                        const float* __restrict__ W_x, const float* __restrict__ W_dt,
                        __hip_bfloat16* __restrict__ wbi, __hip_bfloat16* __restrict__ wbo,
                        __hip_bfloat16* __restrict__ wbig) {
    const int i = blockIdx.x * 256 + threadIdx.x;
    if (i < NWI) {
        wbi[i] = __float2bfloat16(W_in[i]);
    } else if (i < NWI + NWO) {
        const int j = i - NWI;
        wbo[j] = __float2bfloat16(W_out[j]);
    } else if (i < NWI + NWO + NWBIG) {
        const int j = i - NWI - NWO;
        const int r = j / DIN, c = j - r * DIN;
        float v;
        if (r < 32) {
            v = W_x[(size_t)(DTRANK + r) * DIN + c];        // B,C rows
        } else if (r < 32 + DIN) {
            const int d = r - 32;                           // composite dt row
            v = 0.f;
#pragma unroll
            for (int q = 0; q < DTRANK; ++q)
                v += W_dt[d * DTRANK + q] * W_x[(size_t)q * DIN + c];
        } else {
            v = 0.f;                                        // pad rows 416..511
        }
        wbig[j] = __float2bfloat16(v);
    }
}

// ---------------- bf16 NT MFMA GEMM, wide-N shape ----------------
// C[m][n] = sum_k A[m][k]*B[n][k]. BM=64, BK=64 (2x32 slabs/barrier), BN in {192,256}.
// 256 thr = 4 waves in 2x2; wave tile 32 x BN/2; TN = BN/32 frags per wave.
// OUTMODE 0: bf16 row-major ldc            (in_proj -> xzb)
// OUTMODE 1: f32 at out[b][n][l], m=b*L+l  (out_proj)
// OUTMODE 3: x_proj fused: n<32 -> xbc f32(m,32); 32<=n<416 -> dlt f32(m,384)
//            with dlt = softplus(v + 2*b_dt[n-32]); n>=416 dropped
template<int BN, int OUTMODE>
__launch_bounds__(256)
__global__ void k_mfma(const __hip_bfloat16* __restrict__ A,
                       const __hip_bfloat16* __restrict__ B,
                       float* __restrict__ Cf, __hip_bfloat16* __restrict__ Cb,
                       float* __restrict__ Cf2, const float* __restrict__ bdt,
                       int K, int ldc) {
    constexpr int WN = BN / 2;     // wave n extent
    constexpr int TN = WN / 16;    // n frags per wave (6 or 8)
    constexpr int RB = BN / 64;    // B staging rounds per slab (3 or 4)
    __shared__ __align__(16) __hip_bfloat16 sA[2 * 64 * 32];
    __shared__ __align__(16) __hip_bfloat16 sB[2 * BN * 32];

    const int tid = threadIdx.x;
    const int lane = tid & 63;
    const int wave = tid >> 6;
    const int wm = wave >> 1, wn = wave & 1;
    const int m0 = blockIdx.x * 64;
    const int n0 = blockIdx.y * BN;
    const int mlan = lane & 15;
    const int kq = (lane >> 4) * 8;
    const int arow = tid >> 2;             // 0..63
    const int acol = (tid & 3) * 8;        // bf16 col within 32-wide slab

    floatx4 acc[2][TN];
#pragma unroll
    for (int i = 0; i < 2; ++i)
#pragma unroll
        for (int j = 0; j < TN; ++j) acc[i][j] = (floatx4){0.f, 0.f, 0.f, 0.f};

    for (int k0 = 0; k0 < K; k0 += 64) {
        __syncthreads();
#pragma unroll
        for (int kk = 0; kk < 2; ++kk)
            GLOAD_LDS16(&A[(size_t)(m0 + arow) * K + k0 + kk*32 + acol],
                        &sA[kk*2048 + arow*32 + acol]);
#pragma unroll
        for (int kk = 0; kk < 2; ++kk)
#pragma unroll
            for (int r = 0; r < RB; ++r)
                GLOAD_LDS16(&B[(size_t)(n0 + r*64 + arow) * K + k0 + kk*32 + acol],
                            &sB[kk*BN*32 + (r*64 + arow)*32 + acol]);
        __syncthreads();

        short8 af[2][2], bf[2][TN];
#pragma unroll
        for (int kk = 0; kk < 2; ++kk) {
#pragma unroll
            for (int im = 0; im < 2; ++im)
                af[kk][im] = *(const short8*)&sA[kk*2048 + (wm*32 + im*16 + mlan)*32 + kq];
#pragma unroll
            for (int jn = 0; jn < TN; ++jn)
                bf[kk][jn] = *(const short8*)&sB[kk*BN*32 + (wn*WN + jn*16 + mlan)*32 + kq];
        }
#pragma unroll
        for (int kk = 0; kk < 2; ++kk)
#pragma unroll
            for (int im = 0; im < 2; ++im)
#pragma unroll
                for (int jn = 0; jn < TN; ++jn)
                    acc[im][jn] = __builtin_amdgcn_mfma_f32_16x16x32_bf16(
                        af[kk][im], bf[kk][jn], acc[im][jn], 0, 0, 0);
    }

    const int quad = lane >> 4;
#pragma unroll
    for (int im = 0; im < 2; ++im) {
#pragma unroll
        for (int jn = 0; jn < TN; ++jn) {
            const int n = n0 + wn*WN + jn*16 + mlan;
            const int mb = m0 + wm*32 + im*16 + quad*4;
#pragma unroll
            for (int r = 0; r < 4; ++r) {
                const int m = mb + r;
                const float v = acc[im][jn][r];
                if (OUTMODE == 0) {
                    Cb[(size_t)m * ldc + n] = __float2bfloat16(v);
                } else if (OUTMODE == 1) {
                    const int bb = m >> 12, ll = m & (L_SEQ - 1);
                    Cf[((size_t)bb * DIMC + n) * L_SEQ + ll] = v;
                } else {
                    if (n < 32) {
                        Cf[(size_t)m * 32 + n] = v;
                    } else if (n < 32 + DIN) {
                        const int d = n - 32;
                        Cf2[(size_t)m * DIN + d] = softplus_f(v + 2.f * bdt[d]);
                    }
                }
            }
        }
    }
}

// ---------------- depthwise causal conv4 + SiLU: xzb bf16 (stride 768) -> bf16 -----
__launch_bounds__(256)
__global__ void k_conv(const __hip_bfloat16* __restrict__ xz, const float* __restrict__ cw,
                       const float* __restrict__ cb, __hip_bfloat16* __restrict__ xcb) {
    const int idx = blockIdx.x * 256 + threadIdx.x;   // m*DIN + d
    const int d = idx % DIN;
    const int m = idx / DIN;
    const int l = m & (L_SEQ - 1);
    const float4 w4 = *(const float4*)&cw[d * 4];
    float s = cb[d];
    const float w[4] = {w4.x, w4.y, w4.z, w4.w};
#pragma unroll
    for (int k = 0; k < 4; ++k) {
        const int ll = l - 3 + k;
        if (ll >= 0) s += __bfloat162float(xz[(size_t)(m - 3 + k) * DIN2 + d]) * w[k];
    }
    xcb[idx] = __float2bfloat16(silu_f(s));
}

// ---------------- scan phase a: per-chunk partial state + chunk product -----------
// 128 threads own 128 consecutive d; grid (G, 3, B). Prefetch t+1.
__launch_bounds__(128)
__global__ void k_scan_a(const float* __restrict__ dlt, const __hip_bfloat16* __restrict__ xcb,
                         const float* __restrict__ xbc, const float* __restrict__ A_log,
                         float* __restrict__ S, float* __restrict__ P) {
    __shared__ float sBC[T_CHUNK * 32];
    const int tid = threadIdx.x;
    const int g = blockIdx.x, b = blockIdx.z;
    const size_t row0 = (size_t)b * L_SEQ + g * T_CHUNK;
    for (int i = tid; i < T_CHUNK * 32; i += 128)
        sBC[i] = xbc[row0 * 32 + i];
    __syncthreads();
    const int d = blockIdx.y * 128 + tid;
    float A[DSTATE];
#pragma unroll
    for (int n = 0; n < DSTATE; ++n) A[n] = -__expf(A_log[d * DSTATE + n]);
    float h[DSTATE] = {};
    float dsum = 0.f;
    const float* dl = dlt + row0 * DIN + d;
    const __hip_bfloat16* ul = xcb + row0 * DIN + d;
    float dv_n = dl[0];
    float uv_n = __bfloat162float(ul[0]);
    for (int t = 0; t < T_CHUNK; ++t) {
        const float dv = dv_n, uv = uv_n;
        const int tn = (t + 1 < T_CHUNK) ? t + 1 : t;
        dv_n = dl[(size_t)tn * DIN];
        uv_n = __bfloat162float(ul[(size_t)tn * DIN]);
        const float dub = dv * uv;
        dsum += dv;
#pragma unroll
        for (int n = 0; n < DSTATE; ++n) {
            const float e = __expf(dv * A[n]);
            h[n] = e * h[n] + dub * sBC[t*32 + n];
        }
    }
    float* Sp = S + (size_t)g * NCH + (size_t)(b * DIN + d) * DSTATE;
    float* Pp = P + (size_t)g * NCH + (size_t)(b * DIN + d) * DSTATE;
#pragma unroll
    for (int n = 0; n < DSTATE; n += 4) {
        *(float4*)&Sp[n] = make_float4(h[n], h[n+1], h[n+2], h[n+3]);
        *(float4*)&Pp[n] = make_float4(__expf(A[n]*dsum), __expf(A[n+1]*dsum),
                                       __expf(A[n+2]*dsum), __expf(A[n+3]*dsum));
    }
}

// ---------------- scan phase b: sequential combine; S becomes entering state ------
__launch_bounds__(256)
__global__ void k_scan_b(float* __restrict__ Sh, const float* __restrict__ P) {
    const int ch = blockIdx.x * 256 + threadIdx.x;
    float h = 0.f;
    for (int g = 0; g < G_CHUNKS; ++g) {
        const size_t i = (size_t)g * NCH + ch;
        const float s = Sh[i];
        const float p = P[i];
        Sh[i] = h;
        h = p * h + s;
    }
}

// ---------------- scan phase c: replay + y + D*u + gate -> yb bf16 ----------------
__launch_bounds__(128)
__global__ void k_scan_c(const float* __restrict__ dlt, const __hip_bfloat16* __restrict__ xcb,
                         const float* __restrict__ xbc, const float* __restrict__ A_log,
                         const float* __restrict__ Hst, const __hip_bfloat16* __restrict__ xzb,
                         const float* __restrict__ Dv, __hip_bfloat16* __restrict__ yb) {
    __shared__ float sBC[T_CHUNK * 32];
    const int tid = threadIdx.x;
    const int g = blockIdx.x, b = blockIdx.z;
    const size_t row0 = (size_t)b * L_SEQ + g * T_CHUNK;
    for (int i = tid; i < T_CHUNK * 32; i += 128)
        sBC[i] = xbc[row0 * 32 + i];
    __syncthreads();
    const int d = blockIdx.y * 128 + tid;
    float A[DSTATE];
#pragma unroll
    for (int n = 0; n < DSTATE; ++n) A[n] = -__expf(A_log[d * DSTATE + n]);
    float h[DSTATE];
    const float* Hp = Hst + (size_t)g * NCH + (size_t)(b * DIN + d) * DSTATE;
#pragma unroll
    for (int n = 0; n < DSTATE; n += 4) {
        const float4 h4 = *(const float4*)&Hp[n];
        h[n] = h4.x; h[n+1] = h4.y; h[n+2] = h4.z; h[n+3] = h4.w;
    }
    const float Dd = Dv[d];
    const float* dl = dlt + row0 * DIN + d;
    const __hip_bfloat16* ul = xcb + row0 * DIN + d;
    const __hip_bfloat16* zl = xzb + row0 * DIN2 + DIN + d;
    __hip_bfloat16* yl = yb + row0 * DIN + d;
    float dv_n = dl[0];
    float uv_n = __bfloat162float(ul[0]);
    float zz_n = __bfloat162float(zl[0]);
    for (int t = 0; t < T_CHUNK; ++t) {
        const float dv = dv_n, uv = uv_n, zz = zz_n;
        const int tn = (t + 1 < T_CHUNK) ? t + 1 : t;
        dv_n = dl[(size_t)tn * DIN];
        uv_n = __bfloat162float(ul[(size_t)tn * DIN]);
        zz_n = __bfloat162float(zl[(size_t)tn * DIN2]);
        const float dub = dv * uv;
        float y0 = 0.f, y1 = 0.f, y2 = 0.f, y3 = 0.f;
#pragma unroll
        for (int n = 0; n < DSTATE; n += 4) {
            float e;
            e = __expf(dv * A[n  ]); h[n  ] = e * h[n  ] + dub * sBC[t*32 + n  ]; y0 += h[n  ] * sBC[t*32 + 16 + n  ];
            e = __expf(dv * A[n+1]); h[n+1] = e * h[n+1] + dub * sBC[t*32 + n+1]; y1 += h[n+1] * sBC[t*32 + 16 + n+1];
            e = __expf(dv * A[n+2]); h[n+2] = e * h[n+2] + dub * sBC[t*32 + n+2]; y2 += h[n+2] * sBC[t*32 + 16 + n+2];
            e = __expf(dv * A[n+3]); h[n+3] = e * h[n+3] + dub * sBC[t*32 + n+3]; y3 += h[n+3] * sBC[t*32 + 16 + n+3];
        }
        const float y = (y0 + y1) + (y2 + y3);
        yl[(size_t)t * DIN] = __float2bfloat16((y + Dd * uv) * silu_f(zz));
    }
}

// ---------------- launcher ----------------
extern "C" void kernel_launch(void* const* d_in, const int* in_sizes, int n_in,
                              void* d_out, int out_size, void* d_ws, size_t ws_size,
                              hipStream_t stream) {
    const float* x      = (const float*)d_in[0];
    const float* W_in   = (const float*)d_in[1];
    const float* conv_w = (const float*)d_in[2];
    const float* conv_b = (const float*)d_in[3];
    const float* W_x    = (const float*)d_in[4];
    const float* W_dt   = (const float*)d_in[5];
    const float* b_dt   = (const float*)d_in[6];
    const float* A_log  = (const float*)d_in[7];
    const float* Dvec   = (const float*)d_in[8];
    const float* W_out  = (const float*)d_in[9];
    float* out = (float*)d_out;

    char* p = (char*)d_ws;
    __hip_bfloat16* xb   = (__hip_bfloat16*)p; p += (size_t)NM * DIMC * 2;
    __hip_bfloat16* wbi  = (__hip_bfloat16*)p; p += (size_t)NWI * 2;
    __hip_bfloat16* wbo  = (__hip_bfloat16*)p; p += (size_t)NWO * 2;
    __hip_bfloat16* wbig = (__hip_bfloat16*)p; p += (size_t)NWBIG * 2;
    __hip_bfloat16* xzb  = (__hip_bfloat16*)p; p += (size_t)NM * DIN2 * 2;    // 25MB
    __hip_bfloat16* xcb  = (__hip_bfloat16*)p; p += (size_t)NM * DIN * 2;     // 12.6MB
    float*          xbc  = (float*)p;          p += (size_t)NM * 32 * 4;      // 2.1MB
    float*          dlt  = (float*)p;          p += (size_t)NM * DIN * 4;     // 25MB
    __hip_bfloat16* yb   = (__hip_bfloat16*)p; p += (size_t)NM * DIN * 2;     // 12.6MB
    float*          S    = (float*)p;          p += (size_t)G_CHUNKS * NCH * 4;
    float*          P    = (float*)p;          p += (size_t)G_CHUNKS * NCH * 4;

    // 1. weight conversion + composite dt weight; input transpose+convert
    k_cvt_w<<<dim3((NWI + NWO + NWBIG + 255) / 256), 256, 0, stream>>>(
        W_in, W_out, W_x, W_dt, wbi, wbo, wbig);
    k_cvt_x<<<dim3(L_SEQ/32, DIMC/32, NB), dim3(32, 8), 0, stream>>>(x, xb);
    // 2. in_proj: xzb(m,768) bf16 = xb(m,192) @ wbi(768,192)^T   [BN=256, 3 n-tiles]
    k_mfma<256, 0><<<dim3(NM/64, DIN2/256), 256, 0, stream>>>(
        xb, wbi, nullptr, xzb, nullptr, nullptr, DIMC, DIN2);
    // 3. depthwise causal conv + silu -> xcb bf16
    k_conv<<<dim3((NM*(size_t)DIN)/256), 256, 0, stream>>>(xzb, conv_w, conv_b, xcb);
    // 4. fused x_proj + dt_proj: xbc(m,32) f32, dlt(m,384)=softplus f32 [BN=256, 2 tiles]
    k_mfma<256, 3><<<dim3(NM/64, NBIG/256), 256, 0, stream>>>(
        xcb, wbig, xbc, nullptr, dlt, b_dt, DIN, 0);
    // 5. chunked selective scan (128-thr blocks, d split by 3)
    k_scan_a<<<dim3(G_CHUNKS, 3, NB), 128, 0, stream>>>(dlt, xcb, xbc, A_log, S, P);
    k_scan_b<<<dim3(NCH/256), 256, 0, stream>>>(S, P);
    k_scan_c<<<dim3(G_CHUNKS, 3, NB), 128, 0, stream>>>(dlt, xcb, xbc, A_log, S, xzb, Dvec, yb);
    // 6. out_proj: out(b,192,l) = yb(m,384) @ wbo(192,384)^T   [BN=192, 1 n-tile]
    k_mfma<192, 1><<<dim3(NM/64, 1), 256, 0, stream>>>(
        yb, wbo, out, nullptr, nullptr, nullptr, DIN, 0);
}

// Round 7
// 232.174 us; speedup vs baseline: 1.1254x; 1.1254x over previous
//
#include <hip/hip_runtime.h>
#include <hip/hip_bf16.h>
#include <math.h>

// ---------------- problem constants ----------------
#define L_SEQ 4096            // H*W
#define NB    4
#define DIMC  192
#define DIN   384             // d_inner
#define DIN2  768
#define DTRANK 12
#define DSTATE 16
#define NKX   44              // dt_rank + 2*d_state
#define G_CHUNKS 128
#define T_CHUNK  32           // L_SEQ / G_CHUNKS
#define NCH  (NB*DIN*DSTATE)  // 24576 scan channels
#define NM   (NB*L_SEQ)       // 16384 (b,l) rows
#define NBIG 512              // padded rows of fused x_proj weight (32 BC + 384 dt + pad)

typedef __attribute__((ext_vector_type(8))) short short8;     // 8 bf16 = 4 VGPRs
typedef __attribute__((ext_vector_type(4))) float floatx4;

__device__ __forceinline__ float silu_f(float v) {
    return v / (1.f + __expf(-v));
}
__device__ __forceinline__ float softplus_f(float v) {
    return fmaxf(v, 0.f) + log1pf(__expf(-fabsf(v)));
}
__device__ __forceinline__ float bf2f(unsigned short u) {
    union { unsigned int i; float f; } c; c.i = ((unsigned int)u) << 16; return c.f;
}

// ---------------- convert + transpose x: (b,c,l) f32 -> (b*l, c) bf16 ----------------
__launch_bounds__(256)
__global__ void k_cvt_x(const float* __restrict__ x, __hip_bfloat16* __restrict__ xb) {
    __shared__ float s[32][33];
    const int b = blockIdx.z, c0 = blockIdx.y * 32, l0 = blockIdx.x * 32;
    const int tx = threadIdx.x, ty = threadIdx.y;   // (32, 8)
    const float* xp = x + ((size_t)b * DIMC + c0) * L_SEQ + l0;
#pragma unroll
    for (int r = 0; r < 4; ++r)
        s[ty + r*8][tx] = xp[(size_t)(ty + r*8) * L_SEQ + tx];
    __syncthreads();
    __hip_bfloat16* op = xb + ((size_t)b * L_SEQ + l0) * DIMC + c0;
#pragma unroll
    for (int r = 0; r < 4; ++r) {
        const int lr = ty + r*8;
        op[(size_t)lr * DIMC + tx] = __float2bfloat16(s[tx][lr]);
    }
}

// ------- weights: W_in, W_out -> bf16; build Wbig(512x384) = [Wx[12:44]; Wdt@Wx[:12]; 0] ----
#define NWI (DIN2*DIMC)        // 147456
#define NWO (DIMC*DIN)         // 73728
#define NWBIG (NBIG*DIN)       // 196608
__launch_bounds__(256)
__global__ void k_cvt_w(const float* __restrict__ W_in, const float* __restrict__ W_out,
                        const float* __restrict__ W_x, const float* __restrict__ W_dt,
                        __hip_bfloat16* __restrict__ wbi, __hip_bfloat16* __restrict__ wbo,
                        __hip_bfloat16* __restrict__ wbig) {
    const int i = blockIdx.x * 256 + threadIdx.x;
    if (i < NWI) {
        wbi[i] = __float2bfloat16(W_in[i]);
    } else if (i < NWI + NWO) {
        const int j = i - NWI;
        wbo[j] = __float2bfloat16(W_out[j]);
    } else if (i < NWI + NWO + NWBIG) {
        const int j = i - NWI - NWO;
        const int r = j / DIN, c = j - r * DIN;
        float v;
        if (r < 32) {
            v = W_x[(size_t)(DTRANK + r) * DIN + c];        // B,C rows
        } else if (r < 32 + DIN) {
            const int d = r - 32;                           // composite dt row
            v = 0.f;
#pragma unroll
            for (int q = 0; q < DTRANK; ++q)
                v += W_dt[d * DTRANK + q] * W_x[(size_t)q * DIN + c];
        } else {
            v = 0.f;                                        // pad rows 416..511
        }
        wbig[j] = __float2bfloat16(v);
    }
}

// ---------------- bf16 NT MFMA GEMM, full-K staging (small-K regime) ----------------
// C[m][n] = sum_k A[m][k]*B[n][k]. BM=64. K staged in 192-wide chunks: A(64x192) +
// B(BNx192) -> padded LDS (row stride 200) via VGPR staging. ONE barrier per chunk,
// then 6*2*TN uninterrupted MFMAs per wave. 4 waves 2x2, wave tile 32 x BN/2.
// OUTMODE 0: bf16 row-major ldc            (in_proj -> xzb)
// OUTMODE 1: f32 at out[b][n][l], m=b*L+l  (out_proj)
// OUTMODE 3: x_proj fused: n<32 -> xbc f32(m,32);
//            32<=n<416: dlt_t[(b,d,l)] = softplus(v + 2*b_dt[d]), d=n-32 (TRANSPOSED)
template<int BN, int OUTMODE>
__launch_bounds__(256)
__global__ void k_gemm(const __hip_bfloat16* __restrict__ A,
                       const __hip_bfloat16* __restrict__ B,
                       float* __restrict__ Cf, __hip_bfloat16* __restrict__ Cb,
                       float* __restrict__ Cf2, const float* __restrict__ bdt,
                       int K, int ldc) {
    constexpr int LDK = 200;                 // padded LDS row, elements
    constexpr int WN = BN / 2;
    constexpr int TN = WN / 16;
    constexpr int NCA = 6;                   // A chunks/thread: 64*24/256
    constexpr int NCB = BN * 24 / 256;       // B chunks/thread
    __shared__ __align__(16) __hip_bfloat16 sA[64 * LDK];
    __shared__ __align__(16) __hip_bfloat16 sB[BN * LDK];

    const int tid = threadIdx.x;
    const int lane = tid & 63;
    const int wave = tid >> 6;
    const int wm = wave >> 1, wn = wave & 1;
    const int m0 = blockIdx.x * 64;
    const int n0 = blockIdx.y * BN;
    const int mlan = lane & 15;
    const int kq8 = (lane >> 4) * 8;

    floatx4 acc[2][TN];
#pragma unroll
    for (int i = 0; i < 2; ++i)
#pragma unroll
        for (int j = 0; j < TN; ++j) acc[i][j] = (floatx4){0.f, 0.f, 0.f, 0.f};

    for (int kh = 0; kh < K; kh += 192) {
        if (kh) __syncthreads();
        // stage A 64x192 and B BNx192 via VGPRs into padded LDS
        uint4 va[NCA], vb[NCB];
#pragma unroll
        for (int r = 0; r < NCA; ++r) {
            const int c = r * 256 + tid, row = c / 24, cc = c - row * 24;
            va[r] = *(const uint4*)&A[(size_t)(m0 + row) * K + kh + cc * 8];
        }
#pragma unroll
        for (int r = 0; r < NCB; ++r) {
            const int c = r * 256 + tid, row = c / 24, cc = c - row * 24;
            vb[r] = *(const uint4*)&B[(size_t)(n0 + row) * K + kh + cc * 8];
        }
#pragma unroll
        for (int r = 0; r < NCA; ++r) {
            const int c = r * 256 + tid, row = c / 24, cc = c - row * 24;
            *(uint4*)&sA[row * LDK + cc * 8] = va[r];
        }
#pragma unroll
        for (int r = 0; r < NCB; ++r) {
            const int c = r * 256 + tid, row = c / 24, cc = c - row * 24;
            *(uint4*)&sB[row * LDK + cc * 8] = vb[r];
        }
        __syncthreads();
#pragma unroll
        for (int ks = 0; ks < 6; ++ks) {
            short8 af[2], bf[TN];
#pragma unroll
            for (int im = 0; im < 2; ++im)
                af[im] = *(const short8*)&sA[(wm*32 + im*16 + mlan) * LDK + ks*32 + kq8];
#pragma unroll
            for (int jn = 0; jn < TN; ++jn)
                bf[jn] = *(const short8*)&sB[(wn*WN + jn*16 + mlan) * LDK + ks*32 + kq8];
#pragma unroll
            for (int im = 0; im < 2; ++im)
#pragma unroll
                for (int jn = 0; jn < TN; ++jn)
                    acc[im][jn] = __builtin_amdgcn_mfma_f32_16x16x32_bf16(
                        af[im], bf[jn], acc[im][jn], 0, 0, 0);
        }
    }

    const int quad = lane >> 4;
#pragma unroll
    for (int im = 0; im < 2; ++im) {
#pragma unroll
        for (int jn = 0; jn < TN; ++jn) {
            const int n = n0 + wn*WN + jn*16 + mlan;
            const int mb = m0 + wm*32 + im*16 + quad*4;
#pragma unroll
            for (int r = 0; r < 4; ++r) {
                const int m = mb + r;
                const float v = acc[im][jn][r];
                if (OUTMODE == 0) {
                    Cb[(size_t)m * ldc + n] = __float2bfloat16(v);
                } else if (OUTMODE == 1) {
                    const int bb = m >> 12, ll = m & (L_SEQ - 1);
                    Cf[((size_t)bb * DIMC + n) * L_SEQ + ll] = v;
                } else {
                    const int bb = m >> 12, ll = m & (L_SEQ - 1);
                    if (n < 32) {
                        Cf[(size_t)m * 32 + n] = v;
                    } else if (n < 32 + DIN) {
                        const int d = n - 32;
                        Cf2[((size_t)bb * DIN + d) * L_SEQ + ll] =
                            softplus_f(v + 2.f * bdt[d]);
                    }
                }
            }
        }
    }
}

// ------- depthwise causal conv4 + SiLU, dual output: xcb (m,d) + xcv_t (b,d,l) -------
__launch_bounds__(256)
__global__ void k_conv(const __hip_bfloat16* __restrict__ xz, const float* __restrict__ cw,
                       const float* __restrict__ cb, __hip_bfloat16* __restrict__ xcb,
                       __hip_bfloat16* __restrict__ xcv_t) {
    __shared__ __hip_bfloat16 sIn[67][64];
    const int tid = threadIdx.x;
    const int l0 = blockIdx.x * 64, d0 = blockIdx.y * 64, b = blockIdx.z;
    const int mbase = b * L_SEQ + l0;
    // load rows l0-3 .. l0+63 of x-half, cols d0..d0+63
    for (int i = tid; i < 67 * 8; i += 256) {
        const int row = i >> 3, ch = i & 7;
        uint4 v = {0u, 0u, 0u, 0u};
        if (l0 - 3 + row >= 0)
            v = *(const uint4*)&xz[(size_t)(mbase - 3 + row) * DIN2 + d0 + ch * 8];
        *(uint4*)&sIn[row][ch * 8] = v;
    }
    __syncthreads();
    const int tx = tid & 63, ty = tid >> 6;       // tx = d lane, ty = l group (4)
    const int d = d0 + tx;
    const float4 w4 = *(const float4*)&cw[d * 4];
    const float bias = cb[d];
    unsigned int pk[8];                            // 16 bf16 packed, l-contiguous
#pragma unroll
    for (int i = 0; i < 16; ++i) {
        const int l = ty * 16 + i;
        float s = bias;
        s += bf2f(*(const unsigned short*)&sIn[l + 0][tx]) * w4.x;
        s += bf2f(*(const unsigned short*)&sIn[l + 1][tx]) * w4.y;
        s += bf2f(*(const unsigned short*)&sIn[l + 2][tx]) * w4.z;
        s += bf2f(*(const unsigned short*)&sIn[l + 3][tx]) * w4.w;
        const float v = silu_f(s);
        const __hip_bfloat16 hv = __float2bfloat16(v);
        xcb[(size_t)(mbase + l) * DIN + d] = hv;   // l-major (coalesced over tx)
        unsigned short us = *(const unsigned short*)&hv;
        if (i & 1) pk[i >> 1] |= ((unsigned int)us) << 16;
        else       pk[i >> 1]  = us;
    }
    // transposed write: 16 consecutive l for this d = 32 B
    __hip_bfloat16* dst = xcv_t + ((size_t)b * DIN + d) * L_SEQ + l0 + ty * 16;
    *(uint4*)&dst[0] = *(uint4*)&pk[0];
    *(uint4*)&dst[8] = *(uint4*)&pk[4];
}

// ---------------- scan phase a: register-resident chunk, vector loads -----------
__launch_bounds__(128)
__global__ void k_scan_a(const float* __restrict__ dlt_t, const __hip_bfloat16* __restrict__ xcv_t,
                         const float* __restrict__ xbc, const float* __restrict__ A_log,
                         float* __restrict__ S, float* __restrict__ P) {
    __shared__ float sBC[T_CHUNK * 32];
    const int tid = threadIdx.x;
    const int g = blockIdx.x, b = blockIdx.z;
    const int l0 = g * T_CHUNK;
    const size_t row0 = (size_t)b * L_SEQ + l0;
    for (int i = tid; i < T_CHUNK * 8; i += 128)
        *(float4*)&sBC[i * 4] = *(const float4*)&xbc[row0 * 32 + i * 4];
    const int d = blockIdx.y * 128 + tid;
    const size_t ch_off = ((size_t)b * DIN + d) * L_SEQ + l0;
    floatx4 dv4[8];
#pragma unroll
    for (int i = 0; i < 8; ++i) dv4[i] = *(const floatx4*)&dlt_t[ch_off + i * 4];
    uint4 uvv[4];
#pragma unroll
    for (int i = 0; i < 4; ++i) uvv[i] = *(const uint4*)&xcv_t[ch_off + i * 8];
    float A[DSTATE];
#pragma unroll
    for (int n = 0; n < DSTATE; n += 4) {
        const float4 a4 = *(const float4*)&A_log[d * DSTATE + n];
        A[n] = -__expf(a4.x); A[n+1] = -__expf(a4.y);
        A[n+2] = -__expf(a4.z); A[n+3] = -__expf(a4.w);
    }
    __syncthreads();
    float h[DSTATE] = {};
    float dsum = 0.f;
#pragma unroll
    for (int t = 0; t < T_CHUNK; ++t) {
        const float dv = dv4[t >> 2][t & 3];
        const unsigned int w = ((const unsigned int*)uvv)[t >> 1];
        const float uv = bf2f((t & 1) ? (unsigned short)(w >> 16) : (unsigned short)(w & 0xffff));
        const float dub = dv * uv;
        dsum += dv;
#pragma unroll
        for (int n = 0; n < DSTATE; ++n) {
            const float e = __expf(dv * A[n]);
            h[n] = e * h[n] + dub * sBC[t*32 + n];
        }
    }
    float* Sp = S + (size_t)g * NCH + (size_t)(b * DIN + d) * DSTATE;
    float* Pp = P + (size_t)g * NCH + (size_t)(b * DIN + d) * DSTATE;
#pragma unroll
    for (int n = 0; n < DSTATE; n += 4) {
        *(float4*)&Sp[n] = make_float4(h[n], h[n+1], h[n+2], h[n+3]);
        *(float4*)&Pp[n] = make_float4(__expf(A[n]*dsum), __expf(A[n+1]*dsum),
                                       __expf(A[n+2]*dsum), __expf(A[n+3]*dsum));
    }
}

// ---------------- scan phase b: sequential combine; S becomes entering state ------
__launch_bounds__(256)
__global__ void k_scan_b(float* __restrict__ Sh, const float* __restrict__ P) {
    const int ch = blockIdx.x * 256 + threadIdx.x;
    float h = 0.f;
    for (int g = 0; g < G_CHUNKS; ++g) {
        const size_t i = (size_t)g * NCH + ch;
        const float s = Sh[i];
        const float p = P[i];
        Sh[i] = h;
        h = p * h + s;
    }
}

// ---------------- scan phase c: replay + y + D*u + gate -> yb bf16 ----------------
__launch_bounds__(128)
__global__ void k_scan_c(const float* __restrict__ dlt_t, const __hip_bfloat16* __restrict__ xcv_t,
                         const float* __restrict__ xbc, const float* __restrict__ A_log,
                         const float* __restrict__ Hst, const __hip_bfloat16* __restrict__ xzb,
                         const float* __restrict__ Dv, __hip_bfloat16* __restrict__ yb) {
    __shared__ float sBC[T_CHUNK * 32];
    const int tid = threadIdx.x;
    const int g = blockIdx.x, b = blockIdx.z;
    const int l0 = g * T_CHUNK;
    const size_t row0 = (size_t)b * L_SEQ + l0;
    for (int i = tid; i < T_CHUNK * 8; i += 128)
        *(float4*)&sBC[i * 4] = *(const float4*)&xbc[row0 * 32 + i * 4];
    const int d = blockIdx.y * 128 + tid;
    const size_t ch_off = ((size_t)b * DIN + d) * L_SEQ + l0;
    floatx4 dv4[8];
#pragma unroll
    for (int i = 0; i < 8; ++i) dv4[i] = *(const floatx4*)&dlt_t[ch_off + i * 4];
    uint4 uvv[4];
#pragma unroll
    for (int i = 0; i < 4; ++i) uvv[i] = *(const uint4*)&xcv_t[ch_off + i * 8];
    const __hip_bfloat16* zl = xzb + row0 * DIN2 + DIN + d;
    unsigned short zz[T_CHUNK];
#pragma unroll
    for (int t = 0; t < T_CHUNK; ++t)
        zz[t] = *(const unsigned short*)&zl[(size_t)t * DIN2];
    float A[DSTATE];
#pragma unroll
    for (int n = 0; n < DSTATE; n += 4) {
        const float4 a4 = *(const float4*)&A_log[d * DSTATE + n];
        A[n] = -__expf(a4.x); A[n+1] = -__expf(a4.y);
        A[n+2] = -__expf(a4.z); A[n+3] = -__expf(a4.w);
    }
    float h[DSTATE];
    const float* Hp = Hst + (size_t)g * NCH + (size_t)(b * DIN + d) * DSTATE;
#pragma unroll
    for (int n = 0; n < DSTATE; n += 4) {
        const float4 h4 = *(const float4*)&Hp[n];
        h[n] = h4.x; h[n+1] = h4.y; h[n+2] = h4.z; h[n+3] = h4.w;
    }
    const float Dd = Dv[d];
    __hip_bfloat16* yl = yb + row0 * DIN + d;
    __syncthreads();
#pragma unroll
    for (int t = 0; t < T_CHUNK; ++t) {
        const float dv = dv4[t >> 2][t & 3];
        const unsigned int w = ((const unsigned int*)uvv)[t >> 1];
        const float uv = bf2f((t & 1) ? (unsigned short)(w >> 16) : (unsigned short)(w & 0xffff));
        const float dub = dv * uv;
        float y0 = 0.f, y1 = 0.f, y2 = 0.f, y3 = 0.f;
#pragma unroll
        for (int n = 0; n < DSTATE; n += 4) {
            float e;
            e = __expf(dv * A[n  ]); h[n  ] = e * h[n  ] + dub * sBC[t*32 + n  ]; y0 += h[n  ] * sBC[t*32 + 16 + n  ];
            e = __expf(dv * A[n+1]); h[n+1] = e * h[n+1] + dub * sBC[t*32 + n+1]; y1 += h[n+1] * sBC[t*32 + 16 + n+1];
            e = __expf(dv * A[n+2]); h[n+2] = e * h[n+2] + dub * sBC[t*32 + n+2]; y2 += h[n+2] * sBC[t*32 + 16 + n+2];
            e = __expf(dv * A[n+3]); h[n+3] = e * h[n+3] + dub * sBC[t*32 + n+3]; y3 += h[n+3] * sBC[t*32 + 16 + n+3];
        }
        const float y = (y0 + y1) + (y2 + y3);
        yl[(size_t)t * DIN] = __float2bfloat16((y + Dd * uv) * silu_f(bf2f(zz[t])));
    }
}

// ---------------- launcher ----------------
extern "C" void kernel_launch(void* const* d_in, const int* in_sizes, int n_in,
                              void* d_out, int out_size, void* d_ws, size_t ws_size,
                              hipStream_t stream) {
    const float* x      = (const float*)d_in[0];
    const float* W_in   = (const float*)d_in[1];
    const float* conv_w = (const float*)d_in[2];
    const float* conv_b = (const float*)d_in[3];
    const float* W_x    = (const float*)d_in[4];
    const float* W_dt   = (const float*)d_in[5];
    const float* b_dt   = (const float*)d_in[6];
    const float* A_log  = (const float*)d_in[7];
    const float* Dvec   = (const float*)d_in[8];
    const float* W_out  = (const float*)d_in[9];
    float* out = (float*)d_out;

    char* p = (char*)d_ws;
    __hip_bfloat16* xb    = (__hip_bfloat16*)p; p += (size_t)NM * DIMC * 2;
    __hip_bfloat16* wbi   = (__hip_bfloat16*)p; p += (size_t)NWI * 2;
    __hip_bfloat16* wbo   = (__hip_bfloat16*)p; p += (size_t)NWO * 2;
    __hip_bfloat16* wbig  = (__hip_bfloat16*)p; p += (size_t)NWBIG * 2;
    __hip_bfloat16* xzb   = (__hip_bfloat16*)p; p += (size_t)NM * DIN2 * 2;   // 25MB
    __hip_bfloat16* xcb   = (__hip_bfloat16*)p; p += (size_t)NM * DIN * 2;    // 12.6MB
    __hip_bfloat16* xcv_t = (__hip_bfloat16*)p; p += (size_t)NM * DIN * 2;    // 12.6MB
    float*          xbc   = (float*)p;          p += (size_t)NM * 32 * 4;     // 2.1MB
    float*          dlt_t = (float*)p;          p += (size_t)NM * DIN * 4;    // 25MB
    __hip_bfloat16* yb    = (__hip_bfloat16*)p; p += (size_t)NM * DIN * 2;    // 12.6MB
    float*          S     = (float*)p;          p += (size_t)G_CHUNKS * NCH * 4;
    float*          P     = (float*)p;          p += (size_t)G_CHUNKS * NCH * 4;

    // 1. weight conversion + composite dt weight; input transpose+convert
    k_cvt_w<<<dim3((NWI + NWO + NWBIG + 255) / 256), 256, 0, stream>>>(
        W_in, W_out, W_x, W_dt, wbi, wbo, wbig);
    k_cvt_x<<<dim3(L_SEQ/32, DIMC/32, NB), dim3(32, 8), 0, stream>>>(x, xb);
    // 2. in_proj: xzb(m,768) bf16 = xb(m,192) @ wbi(768,192)^T   [K=192: ONE barrier]
    k_gemm<128, 0><<<dim3(NM/64, DIN2/128), 256, 0, stream>>>(
        xb, wbi, nullptr, xzb, nullptr, nullptr, DIMC, DIN2);
    // 3. depthwise causal conv + silu -> xcb (l-major) + xcv_t (d-major)
    k_conv<<<dim3(L_SEQ/64, DIN/64, NB), 256, 0, stream>>>(xzb, conv_w, conv_b, xcb, xcv_t);
    // 4. fused x_proj + dt_proj: xbc(m,32) f32, dlt_t(b,d,l)=softplus f32
    k_gemm<128, 3><<<dim3(NM/64, NBIG/128), 256, 0, stream>>>(
        xcb, wbig, xbc, nullptr, dlt_t, b_dt, DIN, 0);
    // 5. chunked selective scan (register-resident chunks)
    k_scan_a<<<dim3(G_CHUNKS, 3, NB), 128, 0, stream>>>(dlt_t, xcv_t, xbc, A_log, S, P);
    k_scan_b<<<dim3(NCH/256), 256, 0, stream>>>(S, P);
    k_scan_c<<<dim3(G_CHUNKS, 3, NB), 128, 0, stream>>>(dlt_t, xcv_t, xbc, A_log,
                                                        S, xzb, Dvec, yb);
    // 6. out_proj: out(b,192,l) = yb(m,384) @ wbo(192,384)^T
    k_gemm<96, 1><<<dim3(NM/64, DIMC/96), 256, 0, stream>>>(
        yb, wbo, out, nullptr, nullptr, nullptr, DIN, 0);
}

// Round 8
// 217.066 us; speedup vs baseline: 1.2037x; 1.0696x over previous
//
#include <hip/hip_runtime.h>
#include <hip/hip_bf16.h>
#include <math.h>

// ---------------- problem constants ----------------
#define L_SEQ 4096            // H*W
#define NB    4
#define DIMC  192
#define DIN   384             // d_inner
#define DIN2  768
#define DTRANK 12
#define DSTATE 16
#define NKX   44              // dt_rank + 2*d_state
#define G_CHUNKS 128
#define T_CHUNK  32           // L_SEQ / G_CHUNKS
#define NCH  (NB*DIN*DSTATE)  // 24576 scan channels
#define NM   (NB*L_SEQ)       // 16384 (b,l) rows
#define NBIG 448              // padded rows of fused x_proj weight (32 BC + 384 dt + pad)

typedef __attribute__((ext_vector_type(8))) short short8;     // 8 bf16 = 4 VGPRs
typedef __attribute__((ext_vector_type(4))) float floatx4;

__device__ __forceinline__ float silu_f(float v) {
    return v / (1.f + __expf(-v));
}
// softplus via hardware v_log_f32 (log1pf is a slow libm path).
// For |v| large-negative the 1+e^-|v| rounds to 1 -> returns 0 (vs e^v ~ 1e-8):
// negligible for the scan (dt ~ 0 contributes nothing).
__device__ __forceinline__ float softplus_f(float v) {
    return fmaxf(v, 0.f) + __logf(1.f + __expf(-fabsf(v)));
}
__device__ __forceinline__ float bf2f(unsigned short u) {
    union { unsigned int i; float f; } c; c.i = ((unsigned int)u) << 16; return c.f;
}

// ---------------- convert + transpose x: (b,c,l) f32 -> (b*l, c) bf16 ----------------
__launch_bounds__(256)
__global__ void k_cvt_x(const float* __restrict__ x, __hip_bfloat16* __restrict__ xb) {
    __shared__ float s[32][33];
    const int b = blockIdx.z, c0 = blockIdx.y * 32, l0 = blockIdx.x * 32;
    const int tx = threadIdx.x, ty = threadIdx.y;   // (32, 8)
    const float* xp = x + ((size_t)b * DIMC + c0) * L_SEQ + l0;
#pragma unroll
    for (int r = 0; r < 4; ++r)
        s[ty + r*8][tx] = xp[(size_t)(ty + r*8) * L_SEQ + tx];
    __syncthreads();
    __hip_bfloat16* op = xb + ((size_t)b * L_SEQ + l0) * DIMC + c0;
#pragma unroll
    for (int r = 0; r < 4; ++r) {
        const int lr = ty + r*8;
        op[(size_t)lr * DIMC + tx] = __float2bfloat16(s[tx][lr]);
    }
}

// ------- weights: W_in, W_out -> bf16; build Wbig(448x384) = [Wx[12:44]; Wdt@Wx[:12]; 0] ----
#define NWI (DIN2*DIMC)        // 147456
#define NWO (DIMC*DIN)         // 73728
#define NWBIG (NBIG*DIN)       // 172032
__launch_bounds__(256)
__global__ void k_cvt_w(const float* __restrict__ W_in, const float* __restrict__ W_out,
                        const float* __restrict__ W_x, const float* __restrict__ W_dt,
                        __hip_bfloat16* __restrict__ wbi, __hip_bfloat16* __restrict__ wbo,
                        __hip_bfloat16* __restrict__ wbig) {
    const int i = blockIdx.x * 256 + threadIdx.x;
    if (i < NWI) {
        wbi[i] = __float2bfloat16(W_in[i]);
    } else if (i < NWI + NWO) {
        const int j = i - NWI;
        wbo[j] = __float2bfloat16(W_out[j]);
    } else if (i < NWI + NWO + NWBIG) {
        const int j = i - NWI - NWO;
        const int r = j / DIN, c = j - r * DIN;
        float v;
        if (r < 32) {
            v = W_x[(size_t)(DTRANK + r) * DIN + c];        // B,C rows
        } else if (r < 32 + DIN) {
            const int d = r - 32;                           // composite dt row
            v = 0.f;
#pragma unroll
            for (int q = 0; q < DTRANK; ++q)
                v += W_dt[d * DTRANK + q] * W_x[(size_t)q * DIN + c];
        } else {
            v = 0.f;                                        // pad rows 416..447
        }
        wbig[j] = __float2bfloat16(v);
    }
}

// ---------------- bf16 NT MFMA GEMM, full-K staging (small-K regime) ----------------
// C[m][n] = sum_k A[m][k]*B[n][k]. BM=64. K staged in 192-wide chunks: A(64x192) +
// B(BNx192) -> padded LDS (row stride 200) via VGPR staging. ONE barrier per chunk.
// 4 waves 2x2, wave tile 32 x BN/2.
// OUTMODE 0: bf16 row-major ldc            (in_proj -> xzb)
// OUTMODE 1: f32 at out[b][n][l], m=b*L+l  (out_proj)
// OUTMODE 3: x_proj fused, ALL m-major: n<32 -> xbc f32(m,32);
//            32<=n<416: dlt[m][n-32] = softplus(v + 2*b_dt[n-32]); n>=416 dropped
template<int BN, int OUTMODE>
__launch_bounds__(256)
__global__ void k_gemm(const __hip_bfloat16* __restrict__ A,
                       const __hip_bfloat16* __restrict__ B,
                       float* __restrict__ Cf, __hip_bfloat16* __restrict__ Cb,
                       float* __restrict__ Cf2, const float* __restrict__ bdt,
                       int K, int ldc) {
    constexpr int LDK = 200;                 // padded LDS row, elements
    constexpr int WN = BN / 2;
    constexpr int TN = WN / 16;
    constexpr int NCA = 6;                   // A chunks/thread: 64*24/256
    constexpr int NCB = BN * 24 / 256;       // B chunks/thread
    __shared__ __align__(16) __hip_bfloat16 sA[64 * LDK];
    __shared__ __align__(16) __hip_bfloat16 sB[BN * LDK];

    const int tid = threadIdx.x;
    const int lane = tid & 63;
    const int wave = tid >> 6;
    const int wm = wave >> 1, wn = wave & 1;
    const int m0 = blockIdx.x * 64;
    const int n0 = blockIdx.y * BN;
    const int mlan = lane & 15;
    const int kq8 = (lane >> 4) * 8;

    floatx4 acc[2][TN];
#pragma unroll
    for (int i = 0; i < 2; ++i)
#pragma unroll
        for (int j = 0; j < TN; ++j) acc[i][j] = (floatx4){0.f, 0.f, 0.f, 0.f};

    for (int kh = 0; kh < K; kh += 192) {
        if (kh) __syncthreads();
        uint4 va[NCA], vb[NCB];
#pragma unroll
        for (int r = 0; r < NCA; ++r) {
            const int c = r * 256 + tid, row = c / 24, cc = c - row * 24;
            va[r] = *(const uint4*)&A[(size_t)(m0 + row) * K + kh + cc * 8];
        }
#pragma unroll
        for (int r = 0; r < NCB; ++r) {
            const int c = r * 256 + tid, row = c / 24, cc = c - row * 24;
            vb[r] = *(const uint4*)&B[(size_t)(n0 + row) * K + kh + cc * 8];
        }
#pragma unroll
        for (int r = 0; r < NCA; ++r) {
            const int c = r * 256 + tid, row = c / 24, cc = c - row * 24;
            *(uint4*)&sA[row * LDK + cc * 8] = va[r];
        }
#pragma unroll
        for (int r = 0; r < NCB; ++r) {
            const int c = r * 256 + tid, row = c / 24, cc = c - row * 24;
            *(uint4*)&sB[row * LDK + cc * 8] = vb[r];
        }
        __syncthreads();
#pragma unroll
        for (int ks = 0; ks < 6; ++ks) {
            short8 af[2], bf[TN];
#pragma unroll
            for (int im = 0; im < 2; ++im)
                af[im] = *(const short8*)&sA[(wm*32 + im*16 + mlan) * LDK + ks*32 + kq8];
#pragma unroll
            for (int jn = 0; jn < TN; ++jn)
                bf[jn] = *(const short8*)&sB[(wn*WN + jn*16 + mlan) * LDK + ks*32 + kq8];
#pragma unroll
            for (int im = 0; im < 2; ++im)
#pragma unroll
                for (int jn = 0; jn < TN; ++jn)
                    acc[im][jn] = __builtin_amdgcn_mfma_f32_16x16x32_bf16(
                        af[im], bf[jn], acc[im][jn], 0, 0, 0);
        }
    }

    const int quad = lane >> 4;
#pragma unroll
    for (int im = 0; im < 2; ++im) {
#pragma unroll
        for (int jn = 0; jn < TN; ++jn) {
            const int n = n0 + wn*WN + jn*16 + mlan;
            const int mb = m0 + wm*32 + im*16 + quad*4;
#pragma unroll
            for (int r = 0; r < 4; ++r) {
                const int m = mb + r;
                const float v = acc[im][jn][r];
                if (OUTMODE == 0) {
                    Cb[(size_t)m * ldc + n] = __float2bfloat16(v);
                } else if (OUTMODE == 1) {
                    const int bb = m >> 12, ll = m & (L_SEQ - 1);
                    Cf[((size_t)bb * DIMC + n) * L_SEQ + ll] = v;
                } else {
                    if (n < 32) {
                        Cf[(size_t)m * 32 + n] = v;
                    } else if (n < 32 + DIN) {
                        Cf2[(size_t)m * DIN + (n - 32)] = softplus_f(v + 2.f * bdt[n - 32]);
                    }
                }
            }
        }
    }
}

// ---------------- depthwise causal conv4 + SiLU: xzb bf16 (stride 768) -> bf16 -----
__launch_bounds__(256)
__global__ void k_conv(const __hip_bfloat16* __restrict__ xz, const float* __restrict__ cw,
                       const float* __restrict__ cb, __hip_bfloat16* __restrict__ xcb) {
    const int idx = blockIdx.x * 256 + threadIdx.x;   // m*DIN + d
    const int d = idx % DIN;
    const int m = idx / DIN;
    const int l = m & (L_SEQ - 1);
    const float4 w4 = *(const float4*)&cw[d * 4];
    float s = cb[d];
    const float w[4] = {w4.x, w4.y, w4.z, w4.w};
#pragma unroll
    for (int k = 0; k < 4; ++k) {
        const int ll = l - 3 + k;
        if (ll >= 0) s += __bfloat162float(xz[(size_t)(m - 3 + k) * DIN2 + d]) * w[k];
    }
    xcb[idx] = __float2bfloat16(silu_f(s));
}

// ---------------- scan phase a: m-major upfront loads (32-deep MLP) ---------------
__launch_bounds__(128)
__global__ void k_scan_a(const float* __restrict__ dlt, const __hip_bfloat16* __restrict__ xcb,
                         const float* __restrict__ xbc, const float* __restrict__ A_log,
                         float* __restrict__ S, float* __restrict__ P) {
    __shared__ float sBC[T_CHUNK * 32];
    const int tid = threadIdx.x;
    const int g = blockIdx.x, b = blockIdx.z;
    const int l0 = g * T_CHUNK;
    const size_t row0 = (size_t)b * L_SEQ + l0;
    for (int i = tid; i < T_CHUNK * 8; i += 128)
        *(float4*)&sBC[i * 4] = *(const float4*)&xbc[row0 * 32 + i * 4];
    const int d = blockIdx.y * 128 + tid;
    // upfront coalesced loads: lane d consecutive -> 256B / instr, 32 in flight
    float dv_a[T_CHUNK];
    unsigned short uv_a[T_CHUNK];
#pragma unroll
    for (int t = 0; t < T_CHUNK; ++t)
        dv_a[t] = dlt[(row0 + t) * DIN + d];
#pragma unroll
    for (int t = 0; t < T_CHUNK; ++t)
        uv_a[t] = *(const unsigned short*)&xcb[(row0 + t) * DIN + d];
    float A[DSTATE];
#pragma unroll
    for (int n = 0; n < DSTATE; n += 4) {
        const float4 a4 = *(const float4*)&A_log[d * DSTATE + n];
        A[n] = -__expf(a4.x); A[n+1] = -__expf(a4.y);
        A[n+2] = -__expf(a4.z); A[n+3] = -__expf(a4.w);
    }
    __syncthreads();
    float h[DSTATE] = {};
    float dsum = 0.f;
#pragma unroll
    for (int t = 0; t < T_CHUNK; ++t) {
        const float dv = dv_a[t];
        const float uv = bf2f(uv_a[t]);
        const float dub = dv * uv;
        dsum += dv;
#pragma unroll
        for (int n = 0; n < DSTATE; ++n) {
            const float e = __expf(dv * A[n]);
            h[n] = e * h[n] + dub * sBC[t*32 + n];
        }
    }
    float* Sp = S + (size_t)g * NCH + (size_t)(b * DIN + d) * DSTATE;
    float* Pp = P + (size_t)g * NCH + (size_t)(b * DIN + d) * DSTATE;
#pragma unroll
    for (int n = 0; n < DSTATE; n += 4) {
        *(float4*)&Sp[n] = make_float4(h[n], h[n+1], h[n+2], h[n+3]);
        *(float4*)&Pp[n] = make_float4(__expf(A[n]*dsum), __expf(A[n+1]*dsum),
                                       __expf(A[n+2]*dsum), __expf(A[n+3]*dsum));
    }
}

// ---------------- scan phase b: sequential combine; S becomes entering state ------
__launch_bounds__(256)
__global__ void k_scan_b(float* __restrict__ Sh, const float* __restrict__ P) {
    const int ch = blockIdx.x * 256 + threadIdx.x;
    float h = 0.f;
    for (int g = 0; g < G_CHUNKS; ++g) {
        const size_t i = (size_t)g * NCH + ch;
        const float s = Sh[i];
        const float p = P[i];
        Sh[i] = h;
        h = p * h + s;
    }
}

// ---------------- scan phase c: replay + y + D*u + gate -> yb bf16 ----------------
__launch_bounds__(128)
__global__ void k_scan_c(const float* __restrict__ dlt, const __hip_bfloat16* __restrict__ xcb,
                         const float* __restrict__ xbc, const float* __restrict__ A_log,
                         const float* __restrict__ Hst, const __hip_bfloat16* __restrict__ xzb,
                         const float* __restrict__ Dv, __hip_bfloat16* __restrict__ yb) {
    __shared__ float sBC[T_CHUNK * 32];
    const int tid = threadIdx.x;
    const int g = blockIdx.x, b = blockIdx.z;
    const int l0 = g * T_CHUNK;
    const size_t row0 = (size_t)b * L_SEQ + l0;
    for (int i = tid; i < T_CHUNK * 8; i += 128)
        *(float4*)&sBC[i * 4] = *(const float4*)&xbc[row0 * 32 + i * 4];
    const int d = blockIdx.y * 128 + tid;
    float dv_a[T_CHUNK];
    unsigned short uv_a[T_CHUNK];
    unsigned short zz_a[T_CHUNK];
#pragma unroll
    for (int t = 0; t < T_CHUNK; ++t)
        dv_a[t] = dlt[(row0 + t) * DIN + d];
#pragma unroll
    for (int t = 0; t < T_CHUNK; ++t)
        uv_a[t] = *(const unsigned short*)&xcb[(row0 + t) * DIN + d];
#pragma unroll
    for (int t = 0; t < T_CHUNK; ++t)
        zz_a[t] = *(const unsigned short*)&xzb[(row0 + t) * DIN2 + DIN + d];
    float A[DSTATE];
#pragma unroll
    for (int n = 0; n < DSTATE; n += 4) {
        const float4 a4 = *(const float4*)&A_log[d * DSTATE + n];
        A[n] = -__expf(a4.x); A[n+1] = -__expf(a4.y);
        A[n+2] = -__expf(a4.z); A[n+3] = -__expf(a4.w);
    }
    float h[DSTATE];
    const float* Hp = Hst + (size_t)g * NCH + (size_t)(b * DIN + d) * DSTATE;
#pragma unroll
    for (int n = 0; n < DSTATE; n += 4) {
        const float4 h4 = *(const float4*)&Hp[n];
        h[n] = h4.x; h[n+1] = h4.y; h[n+2] = h4.z; h[n+3] = h4.w;
    }
    const float Dd = Dv[d];
    __hip_bfloat16* yl = yb + row0 * DIN + d;
    __syncthreads();
#pragma unroll
    for (int t = 0; t < T_CHUNK; ++t) {
        const float dv = dv_a[t];
        const float uv = bf2f(uv_a[t]);
        const float dub = dv * uv;
        float y0 = 0.f, y1 = 0.f, y2 = 0.f, y3 = 0.f;
#pragma unroll
        for (int n = 0; n < DSTATE; n += 4) {
            float e;
            e = __expf(dv * A[n  ]); h[n  ] = e * h[n  ] + dub * sBC[t*32 + n  ]; y0 += h[n  ] * sBC[t*32 + 16 + n  ];
            e = __expf(dv * A[n+1]); h[n+1] = e * h[n+1] + dub * sBC[t*32 + n+1]; y1 += h[n+1] * sBC[t*32 + 16 + n+1];
            e = __expf(dv * A[n+2]); h[n+2] = e * h[n+2] + dub * sBC[t*32 + n+2]; y2 += h[n+2] * sBC[t*32 + 16 + n+2];
            e = __expf(dv * A[n+3]); h[n+3] = e * h[n+3] + dub * sBC[t*32 + n+3]; y3 += h[n+3] * sBC[t*32 + 16 + n+3];
        }
        const float y = (y0 + y1) + (y2 + y3);
        yl[(size_t)t * DIN] = __float2bfloat16((y + Dd * uv) * silu_f(bf2f(zz_a[t])));
    }
}

// ---------------- launcher ----------------
extern "C" void kernel_launch(void* const* d_in, const int* in_sizes, int n_in,
                              void* d_out, int out_size, void* d_ws, size_t ws_size,
                              hipStream_t stream) {
    const float* x      = (const float*)d_in[0];
    const float* W_in   = (const float*)d_in[1];
    const float* conv_w = (const float*)d_in[2];
    const float* conv_b = (const float*)d_in[3];
    const float* W_x    = (const float*)d_in[4];
    const float* W_dt   = (const float*)d_in[5];
    const float* b_dt   = (const float*)d_in[6];
    const float* A_log  = (const float*)d_in[7];
    const float* Dvec   = (const float*)d_in[8];
    const float* W_out  = (const float*)d_in[9];
    float* out = (float*)d_out;

    char* p = (char*)d_ws;
    __hip_bfloat16* xb    = (__hip_bfloat16*)p; p += (size_t)NM * DIMC * 2;
    __hip_bfloat16* wbi   = (__hip_bfloat16*)p; p += (size_t)NWI * 2;
    __hip_bfloat16* wbo   = (__hip_bfloat16*)p; p += (size_t)NWO * 2;
    __hip_bfloat16* wbig  = (__hip_bfloat16*)p; p += (size_t)NWBIG * 2;
    __hip_bfloat16* xzb   = (__hip_bfloat16*)p; p += (size_t)NM * DIN2 * 2;   // 25MB
    __hip_bfloat16* xcb   = (__hip_bfloat16*)p; p += (size_t)NM * DIN * 2;    // 12.6MB
    float*          xbc   = (float*)p;          p += (size_t)NM * 32 * 4;     // 2.1MB
    float*          dlt   = (float*)p;          p += (size_t)NM * DIN * 4;    // 25MB
    __hip_bfloat16* yb    = (__hip_bfloat16*)p; p += (size_t)NM * DIN * 2;    // 12.6MB
    float*          S     = (float*)p;          p += (size_t)G_CHUNKS * NCH * 4;
    float*          P     = (float*)p;          p += (size_t)G_CHUNKS * NCH * 4;

    // 1. weight conversion + composite dt weight; input transpose+convert
    k_cvt_w<<<dim3((NWI + NWO + NWBIG + 255) / 256), 256, 0, stream>>>(
        W_in, W_out, W_x, W_dt, wbi, wbo, wbig);
    k_cvt_x<<<dim3(L_SEQ/32, DIMC/32, NB), dim3(32, 8), 0, stream>>>(x, xb);
    // 2. in_proj: xzb(m,768) bf16 = xb(m,192) @ wbi(768,192)^T   [K=192: one barrier]
    k_gemm<128, 0><<<dim3(NM/64, DIN2/128), 256, 0, stream>>>(
        xb, wbi, nullptr, xzb, nullptr, nullptr, DIMC, DIN2);
    // 3. depthwise causal conv + silu -> xcb m-major
    k_conv<<<dim3((NM*(size_t)DIN)/256), 256, 0, stream>>>(xzb, conv_w, conv_b, xcb);
    // 4. fused x_proj + dt_proj: xbc(m,32) f32, dlt(m,384)=softplus f32 [BN=64, 7 tiles]
    k_gemm<64, 3><<<dim3(NM/64, NBIG/64), 256, 0, stream>>>(
        xcb, wbig, xbc, nullptr, dlt, b_dt, DIN, 0);
    // 5. chunked selective scan (m-major upfront loads)
    k_scan_a<<<dim3(G_CHUNKS, 3, NB), 128, 0, stream>>>(dlt, xcb, xbc, A_log, S, P);
    k_scan_b<<<dim3(NCH/256), 256, 0, stream>>>(S, P);
    k_scan_c<<<dim3(G_CHUNKS, 3, NB), 128, 0, stream>>>(dlt, xcb, xbc, A_log,
                                                        S, xzb, Dvec, yb);
    // 6. out_proj: out(b,192,l) = yb(m,384) @ wbo(192,384)^T
    k_gemm<96, 1><<<dim3(NM/64, DIMC/96), 256, 0, stream>>>(
        yb, wbo, out, nullptr, nullptr, nullptr, DIN, 0);
}